// Round 5
// baseline (148.153 us; speedup 1.0000x reference)
//
#include <hip/hip_runtime.h>

#define HW10  163840   // plane stride in floats (128*128*10)
#define TAUC  100.0f

// ws float layout (all zeroed by memset node each call):
#define DOT_OFF 0        // [1024]  sum_k y_i[k]*a_j[k]
#define Y2_OFF  1024     // [32]    sum_k y_i[k]^2
#define A2_OFF  1056     // [32]    sum_k a_j[k]^2
#define US_OFF  1088     // [256]   sum_k (u8_i-u9_j)^2
#define CNT_OFF 1344     // arrival counter (unsigned)
#define ZERO_BYTES 5504

__device__ __forceinline__ float wave_sum(float v) {
    for (int off = 32; off > 0; off >>= 1) v += __shfl_down(v, off, 64);
    return v;
}
__device__ __forceinline__ float wave_min(float v) {
    for (int off = 32; off > 0; off >>= 1) v = fminf(v, __shfl_down(v, off, 64));
    return v;
}

// 256 blocks, each owns (row h = blk>>1, w-half = blk&1):
//   PD: stage center row (32 planes x 66 cols) in LDS, stencil with h+-1 direct
//       loads, Gram-form pair accumulation, atomicAdd partials.
//   US: u[:,h,w-half,8/9], 16x16 pair partials, atomicAdd.
// Last-arriving block performs the scalar epilogue.
__global__ __launch_bounds__(256)
void k_all(const float* __restrict__ x1, const float* __restrict__ x2,
           const float* __restrict__ vs, const float* __restrict__ u,
           const float* __restrict__ dtp, const float* __restrict__ dxp,
           float* __restrict__ ws, float* __restrict__ outp)
{
    __shared__ float sC[32][68];   // center row, cols 0..65 (1..64 = w0..w0+63)
    __shared__ float sA[32][68];   // center values, k-aligned
    __shared__ float sY[32][68];   // y = a + update
    __shared__ float s8[16][68];
    __shared__ float s9[16][68];
    __shared__ float sc0[16], scx[16], scy[16], sdt[16];
    __shared__ unsigned sDone;
    __shared__ float rp[4], ro[4], rm[4];

    int tid = threadIdx.x, blk = blockIdx.x;
    int h = blk >> 1, w0 = (blk & 1) << 6;
    int hm = (h + 127) & 127, hp = (h + 1) & 127;

    if (tid < 16) {
        sc0[tid] = vs[tid * 3 + 0];
        scx[tid] = vs[tid * 3 + 1];
        scy[tid] = vs[tid * 3 + 2];
        sdt[tid] = dtp[tid];
    }

    // ---- stage center rows ----
#pragma unroll
    for (int s = 0; s < 8; ++s) {
        int e = s * 256 + tid;
        int p = e >> 6, wi = e & 63;
        const float* pl = ((p < 16) ? x2 : x1) + (size_t)(p & 15) * HW10;
        sC[p][1 + wi] = pl[(size_t)((h << 7) + w0 + wi) * 10];
    }
    if (tid < 64) {
        int p = tid >> 1, side = tid & 1;
        const float* pl = ((p < 16) ? x2 : x1) + (size_t)(p & 15) * HW10;
        int w = side ? ((w0 + 64) & 127) : ((w0 + 127) & 127);
        sC[p][side ? 65 : 0] = pl[(size_t)((h << 7) + w) * 10];
    }
    // ---- stage u row (t=8,9) ----
#pragma unroll
    for (int s = 0; s < 4; ++s) {
        int e = s * 256 + tid;
        int p = e >> 6, wi = e & 63;
        float2 v = *(const float2*)(u + (size_t)((p * 128 + h) * 128 + w0 + wi) * 10 + 8);
        s8[p][wi] = v.x;
        s9[p][wi] = v.y;
    }
    __syncthreads();

    float dxv = dxp[0];
    float inv_dx = 1.0f / dxv, inv_dx2 = inv_dx * inv_dx;

    // ---- stencil + per-plane self-sums (wave == one plane per s-iter) ----
#pragma unroll
    for (int s = 0; s < 8; ++s) {
        int e = s * 256 + tid;
        int p = e >> 6, wi = e & 63;
        int w = w0 + wi;
        const float* pl = ((p < 16) ? x2 : x1) + (size_t)(p & 15) * HW10;
        float c   = sC[p][1 + wi];
        float awm = sC[p][wi];
        float aw1 = sC[p][2 + wi];
        float ah1 = pl[(size_t)((hp << 7) + w) * 10];
        float ahm = pl[(size_t)((hm << 7) + w) * 10];
        float lap = aw1 + awm + ah1 + ahm - 4.0f * c;
        int bb = p & 15;
        float cx = scx[bb], cy = scy[bb];
        float xt = (cx <= 0.0f) ? (-cx * (c - aw1)) : (cx * (c - awm));
        float yt = (cy >= 0.0f) ? ( cy * (c - ahm)) : (-cy * (c - ah1));
        float y = c - sdt[bb] * (c * (xt + yt)) * inv_dx + sc0[bb] * lap * inv_dx2;
        sA[p][wi] = c;
        sY[p][wi] = y;
        float ys = wave_sum(y * y);
        float as = wave_sum(c * c);
        if ((tid & 63) == 0) {
            atomicAdd(&ws[Y2_OFF + p], ys);
            atomicAdd(&ws[A2_OFF + p], as);
        }
    }
    __syncthreads();

    // ---- PD pair dots (Gram form) ----
    {
        int ti = tid >> 4, tj = tid & 15;
        const float* y0r = &sY[ti][0];
        const float* y1r = &sY[ti + 16][0];
        const float* a0r = &sA[tj][0];
        const float* a1r = &sA[tj + 16][0];
        float d00 = 0.f, d01 = 0.f, d10 = 0.f, d11 = 0.f;
#pragma unroll
        for (int k = 0; k < 64; k += 4) {
            float4 y0 = *(const float4*)(y0r + k);
            float4 y1 = *(const float4*)(y1r + k);
            float4 a0 = *(const float4*)(a0r + k);
            float4 a1 = *(const float4*)(a1r + k);
            d00 += y0.x * a0.x + y0.y * a0.y + y0.z * a0.z + y0.w * a0.w;
            d01 += y0.x * a1.x + y0.y * a1.y + y0.z * a1.z + y0.w * a1.w;
            d10 += y1.x * a0.x + y1.y * a0.y + y1.z * a0.z + y1.w * a0.w;
            d11 += y1.x * a1.x + y1.y * a1.y + y1.z * a1.z + y1.w * a1.w;
        }
        atomicAdd(&ws[DOT_OFF + ti * 32 + tj],             d00);
        atomicAdd(&ws[DOT_OFF + ti * 32 + tj + 16],        d01);
        atomicAdd(&ws[DOT_OFF + (ti + 16) * 32 + tj],      d10);
        atomicAdd(&ws[DOT_OFF + (ti + 16) * 32 + tj + 16], d11);
    }
    // ---- US pairs ----
    {
        int i = tid >> 4, j = tid & 15;
        const float* ar = &s8[i][0];
        const float* br = &s9[j][0];
        float acc = 0.f;
#pragma unroll
        for (int k = 0; k < 64; k += 4) {
            float4 a = *(const float4*)(ar + k);
            float4 c = *(const float4*)(br + k);
            float d;
            d = a.x - c.x; acc += d * d;
            d = a.y - c.y; acc += d * d;
            d = a.z - c.z; acc += d * d;
            d = a.w - c.w; acc += d * d;
        }
        atomicAdd(&ws[US_OFF + i * 16 + j], acc);
    }

    // ---- last-block-done ----
    __threadfence();
    if (tid == 0) sDone = atomicAdd((unsigned*)&ws[CNT_OFF], 1u);
    __syncthreads();
    if (sDone != 255u) return;
    __threadfence();

    // ---- epilogue (atomic-RMW reads for cross-XCD coherence) ----
    float sum_pos = 0.f, sum_om = 0.f, min_s2 = 3.4e38f;
#pragma unroll
    for (int q = 0; q < 4; ++q) {
        int pair = q * 256 + tid;
        int i = pair >> 5, j = pair & 31;
        int bi = i & 15, bj = j & 15;
        float dot = atomicAdd(&ws[DOT_OFF + pair], 0.0f);
        float y2  = atomicAdd(&ws[Y2_OFF + i], 0.0f);
        float a2  = atomicAdd(&ws[A2_OFF + j], 0.0f);
        float us2 = atomicAdd(&ws[US_OFF + bi * 16 + bj], 0.0f);
        float pd2 = fmaxf(y2 + a2 - 2.0f * dot, 0.0f);
        float pd = sqrtf(pd2), us = sqrtf(us2);
        float S = us - pd; S = S * S;
        float S2 = S * S;
        float ti0 = vs[bi * 3 + 0];
        float ti1 = sqrtf(vs[bi * 3 + 1] * vs[bi * 3 + 1] + vs[bi * 3 + 2] * vs[bi * 3 + 2]);
        float tj0 = vs[bj * 3 + 0];
        float tj1 = sqrtf(vs[bj * 3 + 1] * vs[bj * 3 + 1] + vs[bj * 3 + 2] * vs[bj * 3 + 2]);
        float prod = sqrtf(fabsf(ti0 * tj0) + fabsf(ti1 * tj1));
        float nvi = sqrtf(ti0 * ti0 + ti1 * ti1);
        float nvj = sqrtf(tj0 * tj0 + tj1 * tj1);
        float ss = prod / fmaxf(nvi, nvj);
        sum_pos += 0.5f * ss * S2;
        sum_om  += 1.0f - ss;
        min_s2 = fminf(min_s2, S2);
    }
    sum_pos = wave_sum(sum_pos);
    sum_om  = wave_sum(sum_om);
    min_s2  = wave_min(min_s2);
    int wid = tid >> 6, lane = tid & 63;
    if (lane == 0) { rp[wid] = sum_pos; ro[wid] = sum_om; rm[wid] = min_s2; }
    __syncthreads();
    if (tid == 0) {
        float SP = (rp[0] + rp[1]) + (rp[2] + rp[3]);
        float SO = (ro[0] + ro[1]) + (ro[2] + ro[3]);
        float SM = fminf(fminf(rm[0], rm[1]), fminf(rm[2], rm[3]));
        float scal = fmaxf(TAUC - SM, 0.0f);
        outp[0] = (SP + 0.5f * SO * scal) * (1.0f / 1024.0f) * (1.0f / 16.0f);
    }
}

extern "C" void kernel_launch(void* const* d_in, const int* in_sizes, int n_in,
                              void* d_out, int out_size, void* d_ws, size_t ws_size,
                              hipStream_t stream) {
    const float* x1 = (const float*)d_in[0];
    const float* x2 = (const float*)d_in[1];
    const float* vs = (const float*)d_in[2];
    const float* u  = (const float*)d_in[3];
    const float* dt = (const float*)d_in[4];
    const float* dx = (const float*)d_in[5];
    float* ws  = (float*)d_ws;
    float* out = (float*)d_out;

    hipMemsetAsync(ws, 0, ZERO_BYTES, stream);
    k_all<<<256, 256, 0, stream>>>(x1, x2, vs, u, dt, dx, ws, out);
}

// Round 6
// 38.138 us; speedup vs baseline: 3.8846x; 3.8846x over previous
//
#include <hip/hip_runtime.h>

#define HW10  163840   // plane stride in floats (128*128*10)
#define TAUC  100.0f

// ws float layout:
//   PD partials: [0, 128*1024)          [chunk(128)=row h][pair(1024)]
//   US partials: [128*1024, +256*256)   [chunk(256)=row*2+khalf][pair(256)]
#define PDP 0
#define USP (128*1024)

__device__ __forceinline__ float wave_sum(float v) {
    for (int off = 32; off > 0; off >>= 1) v += __shfl_down(v, off, 64);
    return v;
}
__device__ __forceinline__ float wave_min(float v) {
    for (int off = 32; off > 0; off >>= 1) v = fminf(v, __shfl_down(v, off, 64));
    return v;
}

// ---- K1: 256 blocks x 512 threads ----
// blocks 0..127  : PD row h=blk. Stage center row of 32 planes in LDS (w-neighbors
//                  from LDS), h+-1 rows via direct strided loads. 32x32 pair
//                  partials over this row's 128 k, written to private slot.
// blocks 128..255: US row c=blk-128. u[:,c,:,8/9] staged, 16x16 pair partials
//                  in two k-halves.
__global__ __launch_bounds__(512)
void k_main(const float* __restrict__ x1, const float* __restrict__ x2,
            const float* __restrict__ vs, const float* __restrict__ u,
            const float* __restrict__ dtp, const float* __restrict__ dxp,
            float* __restrict__ ws)
{
    __shared__ float sA[32][132];
    __shared__ float sY[32][132];
    __shared__ float sc0[16], scx[16], scy[16], sdt[16];
    int tid = threadIdx.x, blk = blockIdx.x;

    if (blk < 128) {
        int h = blk;
        if (tid < 16) {
            sc0[tid] = vs[tid * 3 + 0];
            scx[tid] = vs[tid * 3 + 1];
            scy[tid] = vs[tid * 3 + 2];
            sdt[tid] = dtp[tid];
        }
        float dxv = dxp[0];
        float inv_dx = 1.0f / dxv, inv_dx2 = inv_dx * inv_dx;
        // stage center row: 32 planes x 128 w
#pragma unroll
        for (int s = 0; s < 8; ++s) {
            int e = s * 512 + tid;
            int p = e >> 7, wi = e & 127;
            const float* pl = ((p < 16) ? x2 : x1) + (size_t)(p & 15) * HW10;
            sA[p][wi] = pl[(size_t)((h << 7) + wi) * 10];
        }
        __syncthreads();
        int hm = (h + 127) & 127, hp = (h + 1) & 127;
        // stencil: w+-1 from LDS, h+-1 from global
#pragma unroll
        for (int s = 0; s < 8; ++s) {
            int e = s * 512 + tid;
            int p = e >> 7, wi = e & 127;
            int b = p & 15;
            const float* pl = ((p < 16) ? x2 : x1) + (size_t)b * HW10;
            float c   = sA[p][wi];
            float awm = sA[p][(wi + 127) & 127];
            float aw1 = sA[p][(wi + 1) & 127];
            float ah1 = pl[(size_t)((hp << 7) + wi) * 10];
            float ahm = pl[(size_t)((hm << 7) + wi) * 10];
            float lap = aw1 + awm + ah1 + ahm - 4.0f * c;
            float cx = scx[b], cy = scy[b];
            float xt = (cx <= 0.0f) ? (-cx * (c - aw1)) : (cx * (c - awm));
            float yt = (cy >= 0.0f) ? ( cy * (c - ahm)) : (-cy * (c - ah1));
            sY[p][wi] = c - sdt[b] * (c * (xt + yt)) * inv_dx + sc0[b] * lap * inv_dx2;
        }
        __syncthreads();
        // pair partials: thread -> (ti, tj) and (ti, tj+16)
        int ti = tid >> 4, tj = tid & 15;
        const float* yr = &sY[ti][0];
        const float* b0r = &sA[tj][0];
        const float* b1r = &sA[tj + 16][0];
        float acc0 = 0.f, acc1 = 0.f;
#pragma unroll 8
        for (int k = 0; k < 128; k += 4) {
            float4 y  = *(const float4*)(yr + k);
            float4 b0 = *(const float4*)(b0r + k);
            float4 b1 = *(const float4*)(b1r + k);
            float d;
            d = y.x - b0.x; acc0 += d * d; d = y.y - b0.y; acc0 += d * d;
            d = y.z - b0.z; acc0 += d * d; d = y.w - b0.w; acc0 += d * d;
            d = y.x - b1.x; acc1 += d * d; d = y.y - b1.y; acc1 += d * d;
            d = y.z - b1.z; acc1 += d * d; d = y.w - b1.w; acc1 += d * d;
        }
        float* P = ws + PDP + blk * 1024;
        P[ti * 32 + tj]      = acc0;
        P[ti * 32 + tj + 16] = acc1;
    } else {
        int c = blk - 128;
        float (*s8)[132] = sA;   // reuse LDS: 16 rows u8
        float (*s9)[132] = sY;   // 16 rows u9
#pragma unroll
        for (int s = 0; s < 4; ++s) {
            int e = s * 512 + tid;
            int p = e >> 7, wi = e & 127;
            float2 v = *(const float2*)(u + (size_t)((p * 128 + c) * 128 + wi) * 10 + 8);
            s8[p][wi] = v.x;
            s9[p][wi] = v.y;
        }
        __syncthreads();
        int th = tid >> 8, pair = tid & 255;
        int i = pair >> 4, j = pair & 15;
        const float* ar = &s8[i][th * 64];
        const float* br = &s9[j][th * 64];
        float acc = 0.f;
#pragma unroll 8
        for (int k = 0; k < 64; k += 4) {
            float4 a = *(const float4*)(ar + k);
            float4 b = *(const float4*)(br + k);
            float d;
            d = a.x - b.x; acc += d * d; d = a.y - b.y; acc += d * d;
            d = a.z - b.z; acc += d * d; d = a.w - b.w; acc += d * d;
        }
        ws[USP + (c * 2 + th) * 256 + pair] = acc;
    }
}

// ---- K2: fold partials + scalar epilogue (1 block, 1024 threads) ----
__global__ __launch_bounds__(1024)
void k_fin(const float* __restrict__ ws, const float* __restrict__ vs,
           float* __restrict__ outp)
{
    int tid = threadIdx.x;                    // pair id 0..1023
    __shared__ float sUS[256];
    __shared__ float rp[16], ro[16], rm[16];
    if (tid < 256) {
        float s = 0.f;
#pragma unroll 8
        for (int b = 0; b < 256; ++b) s += ws[USP + b * 256 + tid];
        sUS[tid] = s;
    }
    float pd2 = 0.f;
#pragma unroll 8
    for (int b = 0; b < 128; ++b) pd2 += ws[PDP + b * 1024 + tid];
    __syncthreads();
    int i = tid >> 5, j = tid & 31;
    int bi = i & 15, bj = j & 15;
    float pd = sqrtf(pd2);
    float us = sqrtf(sUS[bi * 16 + bj]);
    float S = us - pd; S = S * S;
    float S2 = S * S;
    float ti0 = vs[bi * 3 + 0];
    float ti1 = sqrtf(vs[bi * 3 + 1] * vs[bi * 3 + 1] + vs[bi * 3 + 2] * vs[bi * 3 + 2]);
    float tj0 = vs[bj * 3 + 0];
    float tj1 = sqrtf(vs[bj * 3 + 1] * vs[bj * 3 + 1] + vs[bj * 3 + 2] * vs[bj * 3 + 2]);
    float prod = sqrtf(fabsf(ti0 * tj0) + fabsf(ti1 * tj1));
    float nvi = sqrtf(ti0 * ti0 + ti1 * ti1);
    float nvj = sqrtf(tj0 * tj0 + tj1 * tj1);
    float ss = prod / fmaxf(nvi, nvj);
    float pos = 0.5f * ss * S2;
    float om  = 1.0f - ss;
    float sp = wave_sum(pos), so = wave_sum(om), sm = wave_min(S2);
    int wid = tid >> 6, lane = tid & 63;
    if (lane == 0) { rp[wid] = sp; ro[wid] = so; rm[wid] = sm; }
    __syncthreads();
    if (tid == 0) {
        float SP = 0.f, SO = 0.f, SM = rm[0];
        for (int k = 0; k < 16; ++k) { SP += rp[k]; SO += ro[k]; SM = fminf(SM, rm[k]); }
        float scal = fmaxf(TAUC - SM, 0.0f);
        outp[0] = (SP + 0.5f * SO * scal) * (1.0f / 1024.0f) * (1.0f / 16.0f);
    }
}

extern "C" void kernel_launch(void* const* d_in, const int* in_sizes, int n_in,
                              void* d_out, int out_size, void* d_ws, size_t ws_size,
                              hipStream_t stream) {
    const float* x1 = (const float*)d_in[0];
    const float* x2 = (const float*)d_in[1];
    const float* vs = (const float*)d_in[2];
    const float* u  = (const float*)d_in[3];
    const float* dt = (const float*)d_in[4];
    const float* dx = (const float*)d_in[5];
    float* ws  = (float*)d_ws;
    float* out = (float*)d_out;

    k_main<<<256, 512, 0, stream>>>(x1, x2, vs, u, dt, dx, ws);
    k_fin <<<1,  1024, 0, stream>>>(ws, vs, out);
}

// Round 7
// 33.936 us; speedup vs baseline: 4.3656x; 1.1238x over previous
//
#include <hip/hip_runtime.h>

#define HW10  163840   // plane stride in floats (128*128*10)
#define TAUC  100.0f

// ws float layout:
//   PD partials: [0, 128*1024)          [chunk(128)=row h][pair(1024)]
//   US partials: [128*1024, +128*256)   [chunk(128)=row][pair(256)]
#define PDP 0
#define USP (128*1024)

__device__ __forceinline__ float wave_sum(float v) {
    for (int off = 32; off > 0; off >>= 1) v += __shfl_down(v, off, 64);
    return v;
}
__device__ __forceinline__ float wave_min(float v) {
    for (int off = 32; off > 0; off >>= 1) v = fminf(v, __shfl_down(v, off, 64));
    return v;
}

// ---- K1: 256 blocks x 256 threads (R4 structure, 3-load stencil) ----
// blocks 0..127  : PD row h=blk — pass A stages center row of 32 planes in LDS;
//                  pass B reads w+-1 from LDS, h+-1 from global (2 loads/point).
//                  32x32 pair partials over this row's 128 k -> private slot.
// blocks 128..255: US row c=blk-128 — u[:,c,:,8/9], 16x16 pair partials.
__global__ __launch_bounds__(256)
void k_main(const float* __restrict__ x1, const float* __restrict__ x2,
            const float* __restrict__ vs, const float* __restrict__ u,
            const float* __restrict__ dtp, const float* __restrict__ dxp,
            float* __restrict__ ws)
{
    __shared__ float sA[32][132];
    __shared__ float sY[32][132];
    __shared__ float sc0[16], scx[16], scy[16], sdt[16];
    int tid = threadIdx.x, blk = blockIdx.x;

    if (blk < 128) {
        int h = blk;
        if (tid < 16) {
            sc0[tid] = vs[tid * 3 + 0];
            scx[tid] = vs[tid * 3 + 1];
            scy[tid] = vs[tid * 3 + 2];
            sdt[tid] = dtp[tid];
        }
        float dxv = dxp[0];
        float inv_dx = 1.0f / dxv, inv_dx2 = inv_dx * inv_dx;
        // pass A: stage center row (32 planes x 128 w), 16 loads/thread
#pragma unroll
        for (int s = 0; s < 16; ++s) {
            int e = s * 256 + tid;
            int p = e >> 7, wi = e & 127;
            const float* pl = ((p < 16) ? x2 : x1) + (size_t)(p & 15) * HW10;
            sA[p][wi] = pl[(size_t)((h << 7) + wi) * 10];
        }
        __syncthreads();
        int hm = (h + 127) & 127, hp = (h + 1) & 127;
        // pass B: stencil, w+-1 from LDS, h+-1 from global (2 loads/point)
#pragma unroll
        for (int s = 0; s < 16; ++s) {
            int e = s * 256 + tid;
            int p = e >> 7, wi = e & 127;
            int b = p & 15;
            const float* pl = ((p < 16) ? x2 : x1) + (size_t)b * HW10;
            float c   = sA[p][wi];
            float awm = sA[p][(wi + 127) & 127];
            float aw1 = sA[p][(wi + 1) & 127];
            float ah1 = pl[(size_t)((hp << 7) + wi) * 10];
            float ahm = pl[(size_t)((hm << 7) + wi) * 10];
            float lap = aw1 + awm + ah1 + ahm - 4.0f * c;
            float cx = scx[b], cy = scy[b];
            float xt = (cx <= 0.0f) ? (-cx * (c - aw1)) : (cx * (c - awm));
            float yt = (cy >= 0.0f) ? ( cy * (c - ahm)) : (-cy * (c - ah1));
            sY[p][wi] = c - sdt[b] * (c * (xt + yt)) * inv_dx + sc0[b] * lap * inv_dx2;
        }
        __syncthreads();
        // pair partials: 2x2 pairs/thread (R4 inner loop, unchanged)
        int ti = tid >> 4, tj = tid & 15;
        float a00 = 0.f, a01 = 0.f, a10 = 0.f, a11 = 0.f;
#pragma unroll 8
        for (int k = 0; k < 128; k += 4) {
            float4 y0 = *(const float4*)&sY[ti][k];
            float4 y1 = *(const float4*)&sY[ti + 16][k];
            float4 b0 = *(const float4*)&sA[tj][k];
            float4 b1 = *(const float4*)&sA[tj + 16][k];
            float d;
            d = y0.x - b0.x; a00 += d * d; d = y0.y - b0.y; a00 += d * d;
            d = y0.z - b0.z; a00 += d * d; d = y0.w - b0.w; a00 += d * d;
            d = y0.x - b1.x; a01 += d * d; d = y0.y - b1.y; a01 += d * d;
            d = y0.z - b1.z; a01 += d * d; d = y0.w - b1.w; a01 += d * d;
            d = y1.x - b0.x; a10 += d * d; d = y1.y - b0.y; a10 += d * d;
            d = y1.z - b0.z; a10 += d * d; d = y1.w - b0.w; a10 += d * d;
            d = y1.x - b1.x; a11 += d * d; d = y1.y - b1.y; a11 += d * d;
            d = y1.z - b1.z; a11 += d * d; d = y1.w - b1.w; a11 += d * d;
        }
        float* P = ws + PDP + blk * 1024;
        P[ ti       * 32 + tj     ] = a00;
        P[ ti       * 32 + tj + 16] = a01;
        P[(ti + 16) * 32 + tj     ] = a10;
        P[(ti + 16) * 32 + tj + 16] = a11;
    } else {
        int c = blk - 128;
        float (*s8)[132] = sA;
        float (*s9)[132] = sY;
#pragma unroll
        for (int s = 0; s < 8; ++s) {
            int e = s * 256 + tid;            // 0..2047 = plane*128 + w
            int p = e >> 7, w = e & 127;
            float2 v = *(const float2*)(u + (size_t)((p * 128 + c) * 128 + w) * 10 + 8);
            s8[p][w] = v.x;
            s9[p][w] = v.y;
        }
        __syncthreads();
        int i = tid >> 4, j = tid & 15;
        float acc = 0.f;
#pragma unroll 8
        for (int k = 0; k < 128; k += 4) {
            float4 a = *(const float4*)&s8[i][k];
            float4 b = *(const float4*)&s9[j][k];
            float d;
            d = a.x - b.x; acc += d * d; d = a.y - b.y; acc += d * d;
            d = a.z - b.z; acc += d * d; d = a.w - b.w; acc += d * d;
        }
        ws[USP + c * 256 + i * 16 + j] = acc;
    }
}

// ---- K2: fold partials + scalar epilogue (1 block, 1024 threads) ----
__global__ __launch_bounds__(1024)
void k_fin(const float* __restrict__ ws, const float* __restrict__ vs,
           float* __restrict__ outp)
{
    int tid = threadIdx.x;                    // pair id 0..1023
    __shared__ float sUS[256];
    __shared__ float rp[16], ro[16], rm[16];
    if (tid < 256) {
        float s = 0.f;
#pragma unroll 8
        for (int b = 0; b < 128; ++b) s += ws[USP + b * 256 + tid];
        sUS[tid] = s;
    }
    float pd2 = 0.f;
#pragma unroll 8
    for (int b = 0; b < 128; ++b) pd2 += ws[PDP + b * 1024 + tid];
    __syncthreads();
    int i = tid >> 5, j = tid & 31;
    int bi = i & 15, bj = j & 15;
    float pd = sqrtf(pd2);
    float us = sqrtf(sUS[bi * 16 + bj]);
    float S = us - pd; S = S * S;
    float S2 = S * S;
    float ti0 = vs[bi * 3 + 0];
    float ti1 = sqrtf(vs[bi * 3 + 1] * vs[bi * 3 + 1] + vs[bi * 3 + 2] * vs[bi * 3 + 2]);
    float tj0 = vs[bj * 3 + 0];
    float tj1 = sqrtf(vs[bj * 3 + 1] * vs[bj * 3 + 1] + vs[bj * 3 + 2] * vs[bj * 3 + 2]);
    float prod = sqrtf(fabsf(ti0 * tj0) + fabsf(ti1 * tj1));
    float nvi = sqrtf(ti0 * ti0 + ti1 * ti1);
    float nvj = sqrtf(tj0 * tj0 + tj1 * tj1);
    float ss = prod / fmaxf(nvi, nvj);
    float pos = 0.5f * ss * S2;
    float om  = 1.0f - ss;
    float sp = wave_sum(pos), so = wave_sum(om), sm = wave_min(S2);
    int wid = tid >> 6, lane = tid & 63;
    if (lane == 0) { rp[wid] = sp; ro[wid] = so; rm[wid] = sm; }
    __syncthreads();
    if (tid == 0) {
        float SP = 0.f, SO = 0.f, SM = rm[0];
        for (int k = 0; k < 16; ++k) { SP += rp[k]; SO += ro[k]; SM = fminf(SM, rm[k]); }
        float scal = fmaxf(TAUC - SM, 0.0f);
        outp[0] = (SP + 0.5f * SO * scal) * (1.0f / 1024.0f) * (1.0f / 16.0f);
    }
}

extern "C" void kernel_launch(void* const* d_in, const int* in_sizes, int n_in,
                              void* d_out, int out_size, void* d_ws, size_t ws_size,
                              hipStream_t stream) {
    const float* x1 = (const float*)d_in[0];
    const float* x2 = (const float*)d_in[1];
    const float* vs = (const float*)d_in[2];
    const float* u  = (const float*)d_in[3];
    const float* dt = (const float*)d_in[4];
    const float* dx = (const float*)d_in[5];
    float* ws  = (float*)d_ws;
    float* out = (float*)d_out;

    k_main<<<256, 256, 0, stream>>>(x1, x2, vs, u, dt, dx, ws);
    k_fin <<<1,  1024, 0, stream>>>(ws, vs, out);
}